// Round 5
// baseline (232.881 us; speedup 1.0000x reference)
//
#include <hip/hip_runtime.h>

// SimplifyLoss: Chamfer-style loss, fused pair pass + single reduce.
// preds: [8, 2048, 3] f32, gts: [8, 8192, 3] f32, out: scalar f32.
//
// d[b,i,j] = ||gt_i - pred_j||^2.  u-space trick: u = gg_i - 2*dot(g,p)
// (3 pk_fma, no add); colmin_j = pp_j + min_i u  (pp added once per pred at
// store); rowmin_i = min_j (u + pp_j)  (pk_add + v_min3 pairing two preds).
// 12 VALU inst per 4 pairs = 3/pair.
//
// K1 pair_k: grid 1024 = (b, gtblk of 128 gts, pred-half of 1024). All 1024
//   preds staged once in LDS as (-2x,-2y,-2z,pp) float4, pad idx=q+(q>>3)
//   (conflict-free b128 broadcast; verified distinct banks for tx*4 stride).
//   Thread = (tx pred-group 0..31, ty gt-group 0..7): 16 gts in regs (v2f
//   packed), 4 preds/step, 8 steps, no barriers in main loop. Col u-mins
//   shfl-reduced over ty (3 stages) per step; row mins in regs all kernel.
// K2 red_k: grid (8,9). y<8: colmin over 64 gtblk partials -> chunk sum+max
//   -> atomicAdd(acc)/atomicMax(bmax). y==8: row sum of min(2 halves). 72nd
//   block writes out[0] = acc + mean_b(bmax). pair_k blk 0 zero-inits the
//   accumulators (safe: kernel-boundary ordering).

#define BB 8
#define MM 2048
#define NN 8192
#define FINF 3.4e38f

typedef float v2f __attribute__((ext_vector_type(2)));

__device__ __forceinline__ int pad_idx(int q) { return q + (q >> 3); }

__global__ __launch_bounds__(256, 4) void pair_k(const float* __restrict__ preds,
                                                 const float* __restrict__ gts,
                                                 float* __restrict__ rowpart,
                                                 float* __restrict__ colpart,
                                                 float* __restrict__ acc,
                                                 unsigned* __restrict__ bmax,
                                                 unsigned* __restrict__ cnt) {
    const int blk   = blockIdx.x;
    const int b     = blk >> 7;
    const int gtblk = (blk >> 1) & 63;
    const int ph    = blk & 1;          // pred half (0/1)
    const int tid   = threadIdx.x;
    const int tx    = tid >> 3;         // pred group 0..31 (4 preds/step)
    const int ty    = tid & 7;          // gt group 0..7 (16 gts) = lane bits 0..2

    if (blk == 0 && tid < 16) {
        if (tid == 0) { acc[0] = 0.0f; cnt[0] = 0u; }
        if (tid < 8) bmax[tid] = 0u;    // 0.0f bits; identity for max of >= 0
    }

    // 1024 preds as (-2x,-2y,-2z,pp), padded every 8 entries (18.4 KB).
    __shared__ float4 sp4[1152];

    // Stage all preds of this half: 4 preds (3 float4) per thread.
    {
        const float4* pg = (const float4*)(preds + (size_t)(b * MM + ph * 1024) * 3);
        float4 r0 = pg[tid * 3 + 0], r1 = pg[tid * 3 + 1], r2 = pg[tid * 3 + 2];
        float x[4], y[4], z[4];
        x[0] = r0.x; y[0] = r0.y; z[0] = r0.z;
        x[1] = r0.w; y[1] = r1.x; z[1] = r1.y;
        x[2] = r1.z; y[2] = r1.w; z[2] = r2.x;
        x[3] = r2.y; y[3] = r2.z; z[3] = r2.w;
#pragma unroll
        for (int k = 0; k < 4; ++k) {
            const int q = tid * 4 + k;
            sp4[pad_idx(q)] = make_float4(-2.0f * x[k], -2.0f * y[k], -2.0f * z[k],
                                          fmaf(x[k], x[k], fmaf(y[k], y[k], z[k] * z[k])));
        }
    }

    // My 16 gts (48 contiguous floats, 12x b128) -> v2f packed + ||g||^2.
    v2f gx2[8], gy2[8], gz2[8], gg2[8];
    float rmin[16];
    {
        float f[48];
        const float4* g4 = (const float4*)(gts + (size_t)(b * NN + gtblk * 128 + ty * 16) * 3);
#pragma unroll
        for (int k = 0; k < 12; ++k) ((float4*)f)[k] = g4[k];
#pragma unroll
        for (int ip = 0; ip < 8; ++ip) {
            const float x0 = f[6 * ip + 0], y0 = f[6 * ip + 1], z0 = f[6 * ip + 2];
            const float x1 = f[6 * ip + 3], y1 = f[6 * ip + 4], z1 = f[6 * ip + 5];
            gx2[ip] = (v2f){x0, x1};
            gy2[ip] = (v2f){y0, y1};
            gz2[ip] = (v2f){z0, z1};
            gg2[ip] = __builtin_elementwise_fma(gx2[ip], gx2[ip],
                      __builtin_elementwise_fma(gy2[ip], gy2[ip], gz2[ip] * gz2[ip]));
            rmin[2 * ip]     = FINF;
            rmin[2 * ip + 1] = FINF;
        }
    }

    __syncthreads();   // preds staged; no barriers inside main loop

    for (int step = 0; step < 8; ++step) {
        float cmu[4] = {FINF, FINF, FINF, FINF};   // u-space col mins
        float pw[4];

#pragma unroll
        for (int jp = 0; jp < 2; ++jp) {
            const int j0 = jp * 2, j1 = jp * 2 + 1;
            const float4 p0 = sp4[pad_idx(step * 128 + tx * 4 + j0)];
            const float4 p1 = sp4[pad_idx(step * 128 + tx * 4 + j1)];
            pw[j0] = p0.w; pw[j1] = p1.w;
            const v2f p0x = (v2f){p0.x, p0.x}, p0y = (v2f){p0.y, p0.y}, p0z = (v2f){p0.z, p0.z};
            const v2f p1x = (v2f){p1.x, p1.x}, p1y = (v2f){p1.y, p1.y}, p1z = (v2f){p1.z, p1.z};
            const v2f pp0 = (v2f){p0.w, p0.w}, pp1 = (v2f){p1.w, p1.w};

#pragma unroll
            for (int ip = 0; ip < 8; ++ip) {
                // u = gg - 2*dot : 3 pk_fma each
                v2f u0 = __builtin_elementwise_fma(gx2[ip], p0x,
                         __builtin_elementwise_fma(gy2[ip], p0y,
                         __builtin_elementwise_fma(gz2[ip], p0z, gg2[ip])));
                v2f u1 = __builtin_elementwise_fma(gx2[ip], p1x,
                         __builtin_elementwise_fma(gy2[ip], p1y,
                         __builtin_elementwise_fma(gz2[ip], p1z, gg2[ip])));
                // col mins in u-space: v_min3
                cmu[j0] = fminf(fminf(cmu[j0], u0.x), u0.y);
                cmu[j1] = fminf(fminf(cmu[j1], u1.x), u1.y);
                // row mins in d-space: 2 pk_add + 2 v_min3
                v2f d0 = u0 + pp0;
                v2f d1 = u1 + pp1;
                rmin[2 * ip]     = fminf(fminf(rmin[2 * ip], d0.x), d1.x);
                rmin[2 * ip + 1] = fminf(fminf(rmin[2 * ip + 1], d0.y), d1.y);
            }
        }

        // Reduce col u-mins across ty (lane bits 0..2): 3 stages.
#pragma unroll
        for (int m = 1; m < 8; m <<= 1) {
#pragma unroll
            for (int j = 0; j < 4; ++j)
                cmu[j] = fminf(cmu[j], __shfl_xor(cmu[j], m, 64));
        }
        if (ty == 0) {
            float4* dst = (float4*)&colpart[((size_t)b * 64 + gtblk) * MM +
                                            ph * 1024 + step * 128 + tx * 4];
            *dst = make_float4(cmu[0] + pw[0], cmu[1] + pw[1],
                               cmu[2] + pw[2], cmu[3] + pw[3]);
        }
    }

    // Row-min cross-tx reduce; reuse sp4 as scratch (32*128 = 4096 floats).
    float* red = (float*)sp4;
    __syncthreads();   // all waves done reading sp4 as preds
#pragma unroll
    for (int i = 0; i < 16; ++i) red[tx * 128 + ty * 16 + i] = rmin[i];
    __syncthreads();
    if (tid < 128) {
        float m = red[tid];
#pragma unroll
        for (int k = 1; k < 32; ++k) m = fminf(m, red[k * 128 + tid]);
        rowpart[((size_t)b * 2 + ph) * NN + gtblk * 128 + tid] = m;
    }
}

__global__ __launch_bounds__(256) void red_k(const float* __restrict__ rowpart,
                                             const float* __restrict__ colpart,
                                             float* __restrict__ acc,
                                             unsigned* __restrict__ bmax,
                                             unsigned* __restrict__ cnt,
                                             float* __restrict__ out) {
    const int b = blockIdx.x, y = blockIdx.y, tid = threadIdx.x;
    __shared__ float a1[4], a2[4];

    if (y < 8) {
        const int p = y * 256 + tid;
        const float* cp = colpart + (size_t)b * 64 * MM + p;
        float m = FINF;
#pragma unroll 8
        for (int g = 0; g < 64; ++g) m = fminf(m, cp[(size_t)g * MM]);
        float s = m, mx = m;
#pragma unroll
        for (int o = 32; o > 0; o >>= 1) {
            s += __shfl_down(s, o, 64);
            mx = fmaxf(mx, __shfl_down(mx, o, 64));
        }
        const int w = tid >> 6, lane = tid & 63;
        if (lane == 0) { a1[w] = s; a2[w] = mx; }
        __syncthreads();
        if (tid == 0) {
            float cs = a1[0] + a1[1] + a1[2] + a1[3];
            float cm = fmaxf(fmaxf(a2[0], a2[1]), fmaxf(a2[2], a2[3]));
            atomicAdd(acc, cs / (float)(BB * MM));          // loss_1 contribution
            atomicMax(&bmax[b], __float_as_uint(cm));       // per-batch col max
        }
    } else {
        const float* r = rowpart + (size_t)b * 2 * NN;
        float s = 0.0f;
        for (int i = tid; i < NN; i += 256) s += fminf(r[i], r[NN + i]);
#pragma unroll
        for (int o = 32; o > 0; o >>= 1) s += __shfl_down(s, o, 64);
        const int w = tid >> 6, lane = tid & 63;
        if (lane == 0) a1[w] = s;
        __syncthreads();
        if (tid == 0)
            atomicAdd(acc, (a1[0] + a1[1] + a1[2] + a1[3]) / (float)(BB * NN)); // loss_2
    }

    if (tid == 0) {
        __threadfence();
        unsigned old = atomicAdd(cnt, 1u);
        if (old == 71u) {                    // last of 72 blocks
            __threadfence();
            float a = atomicAdd(acc, 0.0f);  // fetch final sum
            float mm = 0.0f;
#pragma unroll
            for (int bb = 0; bb < 8; ++bb)
                mm += __uint_as_float(atomicMax(&bmax[bb], 0u));
            out[0] = a + mm / (float)BB;     // + loss_m
        }
    }
}

extern "C" void kernel_launch(void* const* d_in, const int* in_sizes, int n_in,
                              void* d_out, int out_size, void* d_ws, size_t ws_size,
                              hipStream_t stream) {
    const float* preds = (const float*)d_in[0];
    const float* gts   = (const float*)d_in[1];
    float* out = (float*)d_out;

    // ws (floats): rowpart[2*8*8192] | colpart[8*64*2048] | acc[1] | bmax[8] | cnt[1]
    float* rowpart = (float*)d_ws;
    float* colpart = rowpart + (size_t)2 * BB * NN;
    float* acc     = colpart + (size_t)BB * 64 * MM;
    unsigned* bmax = (unsigned*)(acc + 1);
    unsigned* cnt  = bmax + 8;

    pair_k<<<1024, 256, 0, stream>>>(preds, gts, rowpart, colpart, acc, bmax, cnt);
    red_k<<<dim3(BB, 9), 256, 0, stream>>>(rowpart, colpart, acc, bmax, cnt, out);
}

// Round 6
// 104.814 us; speedup vs baseline: 2.2219x; 2.2219x over previous
//
#include <hip/hip_runtime.h>

// SimplifyLoss: Chamfer-style loss, fused pair pass + single reduce.
// preds: [8, 2048, 3] f32, gts: [8, 8192, 3] f32, out: scalar f32.
//
// u-space trick: u = gg_i - 2*dot(g,p) (3 pk_fma, gg as fma addend);
// colmin_j = pp_j + min_i u (pp added once at store); rowmin_i =
// min_j (u + pp_j) with two preds paired per v_min3. 12 inst / 4 pairs.
//
// K1 pair_k: grid 1024 = (b, gtblk of 128 gts, pred-half of 1024). All 1024
//   preds staged once in LDS as (-2x,-2y,-2z,pp) float4, pad idx=q+(q>>3)
//   (conflict-free b128 broadcast). Thread = (tx pred-group 0..15, ty
//   gt-group 0..15): 8 gts in regs (v2f packed, explicit named unpack — NO
//   local arrays with punned stores; R5's f[48] spilled to scratch, 419 MB
//   FETCH). 8 preds/step, 8 steps, no barriers in main loop. Col u-mins
//   shfl-reduced over ty (4 stages); row mins in regs all kernel.
// K2 red_k: grid (8,9). y<8: colmin over 64 gtblk partials -> chunk sum+max
//   -> atomicAdd(acc)/atomicMax(bmax). y==8: row sum of min(2 halves). 72nd
//   block writes out[0] = acc + mean_b(bmax). pair_k blk 0 zero-inits the
//   accumulators (safe: kernel-boundary ordering).

#define BB 8
#define MM 2048
#define NN 8192
#define FINF 3.4e38f

typedef float v2f __attribute__((ext_vector_type(2)));

__device__ __forceinline__ int pad_idx(int q) { return q + (q >> 3); }

__global__ __launch_bounds__(256, 4) void pair_k(const float* __restrict__ preds,
                                                 const float* __restrict__ gts,
                                                 float* __restrict__ rowpart,
                                                 float* __restrict__ colpart,
                                                 float* __restrict__ acc,
                                                 unsigned* __restrict__ bmax,
                                                 unsigned* __restrict__ cnt) {
    const int blk   = blockIdx.x;
    const int b     = blk >> 7;
    const int gtblk = (blk >> 1) & 63;
    const int ph    = blk & 1;          // pred half (0/1)
    const int tid   = threadIdx.x;
    const int tx    = tid >> 4;         // pred group 0..15 (8 preds/step)
    const int ty    = tid & 15;         // gt group 0..15 (8 gts) = lane bits 0..3

    if (blk == 0 && tid < 16) {
        if (tid == 0) { acc[0] = 0.0f; cnt[0] = 0u; }
        if (tid < 8) bmax[tid] = 0u;    // 0.0f bits; identity for max of >= 0
    }

    // 1024 preds as (-2x,-2y,-2z,pp), padded every 8 entries (18.4 KB).
    __shared__ float4 sp4[1152];

    // Stage all preds of this half: 4 preds (3 float4) per thread.
    {
        const float4* pg = (const float4*)(preds + (size_t)(b * MM + ph * 1024) * 3);
        float4 r0 = pg[tid * 3 + 0], r1 = pg[tid * 3 + 1], r2 = pg[tid * 3 + 2];
        float x0 = r0.x, y0 = r0.y, z0 = r0.z;
        float x1 = r0.w, y1 = r1.x, z1 = r1.y;
        float x2 = r1.z, y2 = r1.w, z2 = r2.x;
        float x3 = r2.y, y3 = r2.z, z3 = r2.w;
        const int q = tid * 4;
        sp4[pad_idx(q + 0)] = make_float4(-2.0f * x0, -2.0f * y0, -2.0f * z0,
                                          fmaf(x0, x0, fmaf(y0, y0, z0 * z0)));
        sp4[pad_idx(q + 1)] = make_float4(-2.0f * x1, -2.0f * y1, -2.0f * z1,
                                          fmaf(x1, x1, fmaf(y1, y1, z1 * z1)));
        sp4[pad_idx(q + 2)] = make_float4(-2.0f * x2, -2.0f * y2, -2.0f * z2,
                                          fmaf(x2, x2, fmaf(y2, y2, z2 * z2)));
        sp4[pad_idx(q + 3)] = make_float4(-2.0f * x3, -2.0f * y3, -2.0f * z3,
                                          fmaf(x3, x3, fmaf(y3, y3, z3 * z3)));
    }

    // My 8 gts (24 contiguous floats, 6x b128) -> v2f packed + ||g||^2.
    // Explicit named unpack only (no punned local arrays!).
    v2f gx2[4], gy2[4], gz2[4], gg2[4];
    float rmin[8];
    {
        const float4* g4 = (const float4*)(gts + (size_t)(b * NN + gtblk * 128 + ty * 8) * 3);
        float4 a0 = g4[0], a1 = g4[1], a2 = g4[2], a3 = g4[3], a4 = g4[4], a5 = g4[5];
        gx2[0] = (v2f){a0.x, a0.w}; gy2[0] = (v2f){a0.y, a1.x}; gz2[0] = (v2f){a0.z, a1.y};
        gx2[1] = (v2f){a1.z, a2.y}; gy2[1] = (v2f){a1.w, a2.z}; gz2[1] = (v2f){a2.x, a2.w};
        gx2[2] = (v2f){a3.x, a3.w}; gy2[2] = (v2f){a3.y, a4.x}; gz2[2] = (v2f){a3.z, a4.y};
        gx2[3] = (v2f){a4.z, a5.y}; gy2[3] = (v2f){a4.w, a5.z}; gz2[3] = (v2f){a5.x, a5.w};
#pragma unroll
        for (int ip = 0; ip < 4; ++ip) {
            gg2[ip] = __builtin_elementwise_fma(gx2[ip], gx2[ip],
                      __builtin_elementwise_fma(gy2[ip], gy2[ip], gz2[ip] * gz2[ip]));
            rmin[2 * ip]     = FINF;
            rmin[2 * ip + 1] = FINF;
        }
    }

    __syncthreads();   // preds staged; no barriers inside main loop

    for (int step = 0; step < 8; ++step) {
        float cmu[8] = {FINF, FINF, FINF, FINF, FINF, FINF, FINF, FINF};
        float pw[8];

#pragma unroll
        for (int jp = 0; jp < 4; ++jp) {
            const int j0 = 2 * jp, j1 = 2 * jp + 1;
            const float4 p0 = sp4[pad_idx(step * 128 + tx * 8 + j0)];
            const float4 p1 = sp4[pad_idx(step * 128 + tx * 8 + j1)];
            pw[j0] = p0.w; pw[j1] = p1.w;
            const v2f p0x = (v2f){p0.x, p0.x}, p0y = (v2f){p0.y, p0.y}, p0z = (v2f){p0.z, p0.z};
            const v2f p1x = (v2f){p1.x, p1.x}, p1y = (v2f){p1.y, p1.y}, p1z = (v2f){p1.z, p1.z};
            const v2f pp0 = (v2f){p0.w, p0.w}, pp1 = (v2f){p1.w, p1.w};

#pragma unroll
            for (int ip = 0; ip < 4; ++ip) {
                // u = gg - 2*dot : 3 pk_fma per pred
                v2f u0 = __builtin_elementwise_fma(gx2[ip], p0x,
                         __builtin_elementwise_fma(gy2[ip], p0y,
                         __builtin_elementwise_fma(gz2[ip], p0z, gg2[ip])));
                v2f u1 = __builtin_elementwise_fma(gx2[ip], p1x,
                         __builtin_elementwise_fma(gy2[ip], p1y,
                         __builtin_elementwise_fma(gz2[ip], p1z, gg2[ip])));
                // col mins in u-space: v_min3
                cmu[j0] = fminf(fminf(cmu[j0], u0.x), u0.y);
                cmu[j1] = fminf(fminf(cmu[j1], u1.x), u1.y);
                // row mins: 2 pk_add then v_min3 pairing the two preds
                v2f d0 = u0 + pp0;
                v2f d1 = u1 + pp1;
                rmin[2 * ip]     = fminf(fminf(rmin[2 * ip], d0.x), d1.x);
                rmin[2 * ip + 1] = fminf(fminf(rmin[2 * ip + 1], d0.y), d1.y);
            }
        }

        // Reduce col u-mins across ty (lane bits 0..3): 4 stages.
#pragma unroll
        for (int m = 1; m < 16; m <<= 1) {
#pragma unroll
            for (int j = 0; j < 8; ++j)
                cmu[j] = fminf(cmu[j], __shfl_xor(cmu[j], m, 64));
        }
        if (ty == 0) {
            float4* dst = (float4*)&colpart[((size_t)b * 64 + gtblk) * MM +
                                            ph * 1024 + step * 128 + tx * 8];
            dst[0] = make_float4(cmu[0] + pw[0], cmu[1] + pw[1],
                                 cmu[2] + pw[2], cmu[3] + pw[3]);
            dst[1] = make_float4(cmu[4] + pw[4], cmu[5] + pw[5],
                                 cmu[6] + pw[6], cmu[7] + pw[7]);
        }
    }

    // Row-min cross-tx reduce; reuse sp4 as scratch (16*128 = 2048 floats).
    float* red = (float*)sp4;
    __syncthreads();   // all waves done reading sp4 as preds
#pragma unroll
    for (int i = 0; i < 8; ++i) red[tx * 128 + ty * 8 + i] = rmin[i];
    __syncthreads();
    if (tid < 128) {
        float m = red[tid];
#pragma unroll
        for (int k = 1; k < 16; ++k) m = fminf(m, red[k * 128 + tid]);
        rowpart[((size_t)b * 2 + ph) * NN + gtblk * 128 + tid] = m;
    }
}

__global__ __launch_bounds__(256) void red_k(const float* __restrict__ rowpart,
                                             const float* __restrict__ colpart,
                                             float* __restrict__ acc,
                                             unsigned* __restrict__ bmax,
                                             unsigned* __restrict__ cnt,
                                             float* __restrict__ out) {
    const int b = blockIdx.x, y = blockIdx.y, tid = threadIdx.x;
    __shared__ float a1[4], a2[4];

    if (y < 8) {
        const int p = y * 256 + tid;
        const float* cp = colpart + (size_t)b * 64 * MM + p;
        float m = FINF;
#pragma unroll 8
        for (int g = 0; g < 64; ++g) m = fminf(m, cp[(size_t)g * MM]);
        float s = m, mx = m;
#pragma unroll
        for (int o = 32; o > 0; o >>= 1) {
            s += __shfl_down(s, o, 64);
            mx = fmaxf(mx, __shfl_down(mx, o, 64));
        }
        const int w = tid >> 6, lane = tid & 63;
        if (lane == 0) { a1[w] = s; a2[w] = mx; }
        __syncthreads();
        if (tid == 0) {
            float cs = a1[0] + a1[1] + a1[2] + a1[3];
            float cm = fmaxf(fmaxf(a2[0], a2[1]), fmaxf(a2[2], a2[3]));
            atomicAdd(acc, cs / (float)(BB * MM));          // loss_1 contribution
            atomicMax(&bmax[b], __float_as_uint(cm));       // per-batch col max
        }
    } else {
        const float* r = rowpart + (size_t)b * 2 * NN;
        float s = 0.0f;
        for (int i = tid; i < NN; i += 256) s += fminf(r[i], r[NN + i]);
#pragma unroll
        for (int o = 32; o > 0; o >>= 1) s += __shfl_down(s, o, 64);
        const int w = tid >> 6, lane = tid & 63;
        if (lane == 0) a1[w] = s;
        __syncthreads();
        if (tid == 0)
            atomicAdd(acc, (a1[0] + a1[1] + a1[2] + a1[3]) / (float)(BB * NN)); // loss_2
    }

    if (tid == 0) {
        __threadfence();
        unsigned old = atomicAdd(cnt, 1u);
        if (old == 71u) {                    // last of 72 blocks
            __threadfence();
            float a = atomicAdd(acc, 0.0f);  // fetch final sum
            float mm = 0.0f;
#pragma unroll
            for (int bb = 0; bb < 8; ++bb)
                mm += __uint_as_float(atomicMax(&bmax[bb], 0u));
            out[0] = a + mm / (float)BB;     // + loss_m
        }
    }
}

extern "C" void kernel_launch(void* const* d_in, const int* in_sizes, int n_in,
                              void* d_out, int out_size, void* d_ws, size_t ws_size,
                              hipStream_t stream) {
    const float* preds = (const float*)d_in[0];
    const float* gts   = (const float*)d_in[1];
    float* out = (float*)d_out;

    // ws (floats): rowpart[2*8*8192] | colpart[8*64*2048] | acc[1] | bmax[8] | cnt[1]
    float* rowpart = (float*)d_ws;
    float* colpart = rowpart + (size_t)2 * BB * NN;
    float* acc     = colpart + (size_t)BB * 64 * MM;
    unsigned* bmax = (unsigned*)(acc + 1);
    unsigned* cnt  = bmax + 8;

    pair_k<<<1024, 256, 0, stream>>>(preds, gts, rowpart, colpart, acc, bmax, cnt);
    red_k<<<dim3(BB, 9), 256, 0, stream>>>(rowpart, colpart, acc, bmax, cnt, out);
}

// Round 7
// 97.780 us; speedup vs baseline: 2.3817x; 1.0719x over previous
//
#include <hip/hip_runtime.h>

// SimplifyLoss: Chamfer-style loss, fused pair pass + single reduce.
// preds: [8, 2048, 3] f32, gts: [8, 8192, 3] f32, out: scalar f32.
//
// d[b,i,j] = ||gt_i - pred_j||^2 = gg_i + (pp_j - 2*dot(g_i,p_j))
// loss = mean_{b,j} colmin + mean_{b,i} rowmin + mean_b max_j colmin
//
// R4-proven structure (96.1 us). Per 2 pairs: 3 pk_fma + 1 pk_add +
// 2 pk_min = 6 inst = 3 inst/pair — the arithmetic floor for this layout.
// (R6's scalar-min3 variant regressed: v_min3 doesn't form without
// fast-math, costing 4 inst/pair. R5's 16-gt retile spilled to scratch.)
//
// K1 pair_k: grid 1024 = (b, gtblk of 128 gts, pred-half of 1024). All 1024
//   preds staged once in LDS as (-2x,-2y,-2z,pp) float4, pad idx=q+(q>>3)
//   (conflict-free b128 broadcast), so the 8-step main loop has NO barriers.
//   Thread = (tx pred-group 0..15, ty gt-group 0..15): 8 gts fixed in regs
//   (v2f packed for v_pk_fma_f32, explicit named unpack — no punned local
//   arrays), 8 preds/step from LDS. Row-mins in regs all kernel; col-mins
//   per step shfl-reduced over ty (lane bits 0..3) -> partials.
// K2 red_k: grid (8,9). y<8: colmin over 64 gtblk partials -> chunk sum+max
//   -> atomicAdd(acc)/atomicMax(bmax). y==8: row sum of min(2 halves). 72nd
//   block writes out[0] = acc + mean_b(bmax). pair_k blk 0 zero-inits the
//   accumulators (safe: kernel-boundary ordering).

#define BB 8
#define MM 2048
#define NN 8192

typedef float v2f __attribute__((ext_vector_type(2)));

__device__ __forceinline__ int pad_idx(int q) { return q + (q >> 3); }

__global__ __launch_bounds__(256, 4) void pair_k(const float* __restrict__ preds,
                                                 const float* __restrict__ gts,
                                                 float* __restrict__ rowpart,
                                                 float* __restrict__ colpart,
                                                 float* __restrict__ acc,
                                                 unsigned* __restrict__ bmax,
                                                 unsigned* __restrict__ cnt) {
    const int blk   = blockIdx.x;
    const int b     = blk >> 7;
    const int gtblk = (blk >> 1) & 63;
    const int ph    = blk & 1;          // pred half (0/1)
    const int tid   = threadIdx.x;
    const int tx    = tid >> 4;         // pred slot group 0..15
    const int ty    = tid & 15;         // gt group 0..15 (= lane bits 0..3)

    if (blk == 0 && tid < 16) {
        if (tid == 0) { acc[0] = 0.0f; cnt[0] = 0u; }
        if (tid < 8) bmax[tid] = 0u;    // 0-bits == 0.0f, identity for max >= 0
    }

    // 1024 preds as (-2x,-2y,-2z,pp), padded every 8 entries (18.4 KB).
    __shared__ float4 sp4[1152];

    // Stage all preds of this half once: 4 preds (3 float4) per thread.
    {
        const float4* pg = (const float4*)(preds + (size_t)(b * MM + ph * 1024) * 3);
        float4 r0 = pg[tid * 3 + 0], r1 = pg[tid * 3 + 1], r2 = pg[tid * 3 + 2];
        float x0 = r0.x, y0 = r0.y, z0 = r0.z;
        float x1 = r0.w, y1 = r1.x, z1 = r1.y;
        float x2 = r1.z, y2 = r1.w, z2 = r2.x;
        float x3 = r2.y, y3 = r2.z, z3 = r2.w;
        const int q = tid * 4;
        sp4[pad_idx(q + 0)] = make_float4(-2.0f * x0, -2.0f * y0, -2.0f * z0,
                                          fmaf(x0, x0, fmaf(y0, y0, z0 * z0)));
        sp4[pad_idx(q + 1)] = make_float4(-2.0f * x1, -2.0f * y1, -2.0f * z1,
                                          fmaf(x1, x1, fmaf(y1, y1, z1 * z1)));
        sp4[pad_idx(q + 2)] = make_float4(-2.0f * x2, -2.0f * y2, -2.0f * z2,
                                          fmaf(x2, x2, fmaf(y2, y2, z2 * z2)));
        sp4[pad_idx(q + 3)] = make_float4(-2.0f * x3, -2.0f * y3, -2.0f * z3,
                                          fmaf(x3, x3, fmaf(y3, y3, z3 * z3)));
    }

    // My 8 gts (24 contiguous floats, 6x b128) -> v2f packed + ||g||^2.
    v2f gx2[4], gy2[4], gz2[4], gg2[4], rmin2[4];
    {
        const float4* g4 = (const float4*)(gts + (size_t)(b * NN + gtblk * 128 + ty * 8) * 3);
        float4 a0 = g4[0], a1 = g4[1], a2 = g4[2], a3 = g4[3], a4 = g4[4], a5 = g4[5];
        gx2[0] = (v2f){a0.x, a0.w}; gy2[0] = (v2f){a0.y, a1.x}; gz2[0] = (v2f){a0.z, a1.y};
        gx2[1] = (v2f){a1.z, a2.y}; gy2[1] = (v2f){a1.w, a2.z}; gz2[1] = (v2f){a2.x, a2.w};
        gx2[2] = (v2f){a3.x, a3.w}; gy2[2] = (v2f){a3.y, a4.x}; gz2[2] = (v2f){a3.z, a4.y};
        gx2[3] = (v2f){a4.z, a5.y}; gy2[3] = (v2f){a4.w, a5.z}; gz2[3] = (v2f){a5.x, a5.w};
#pragma unroll
        for (int ip = 0; ip < 4; ++ip) {
            gg2[ip] = __builtin_elementwise_fma(gx2[ip], gx2[ip],
                      __builtin_elementwise_fma(gy2[ip], gy2[ip], gz2[ip] * gz2[ip]));
            rmin2[ip] = (v2f){3.4e38f, 3.4e38f};
        }
    }

    __syncthreads();   // preds staged; no barriers needed inside main loop

    for (int step = 0; step < 8; ++step) {
        v2f cmin2[8];
#pragma unroll
        for (int j = 0; j < 8; ++j) cmin2[j] = (v2f){3.4e38f, 3.4e38f};

#pragma unroll
        for (int j = 0; j < 8; ++j) {
            const float4 p = sp4[pad_idx(step * 128 + tx * 8 + j)];
            const v2f px2 = (v2f){p.x, p.x};
            const v2f py2 = (v2f){p.y, p.y};
            const v2f pz2 = (v2f){p.z, p.z};
            const v2f pp2 = (v2f){p.w, p.w};
#pragma unroll
            for (int ip = 0; ip < 4; ++ip) {
                v2f t = __builtin_elementwise_fma(gx2[ip], px2, pp2);
                t     = __builtin_elementwise_fma(gy2[ip], py2, t);
                t     = __builtin_elementwise_fma(gz2[ip], pz2, t);
                v2f d = gg2[ip] + t;
                rmin2[ip] = __builtin_elementwise_min(rmin2[ip], d);
                cmin2[j]  = __builtin_elementwise_min(cmin2[j], d);
            }
        }

        // Collapse pack-pair, reduce across ty (lane bits 0..3), store partial.
        float cmin[8];
#pragma unroll
        for (int j = 0; j < 8; ++j) cmin[j] = fminf(cmin2[j].x, cmin2[j].y);
#pragma unroll
        for (int m = 1; m < 16; m <<= 1) {
#pragma unroll
            for (int j = 0; j < 8; ++j)
                cmin[j] = fminf(cmin[j], __shfl_xor(cmin[j], m, 64));
        }
        if (ty == 0) {
            float4* dst = (float4*)&colpart[((size_t)b * 64 + gtblk) * MM +
                                            ph * 1024 + step * 128 + tx * 8];
            dst[0] = make_float4(cmin[0], cmin[1], cmin[2], cmin[3]);
            dst[1] = make_float4(cmin[4], cmin[5], cmin[6], cmin[7]);
        }
    }

    // Row-min cross-tx reduce; reuse sp4 as scratch (2048 floats needed).
    float* red = (float*)sp4;
    __syncthreads();   // all waves done reading sp4 as preds
#pragma unroll
    for (int ip = 0; ip < 4; ++ip) {
        red[tx * 128 + ty * 8 + 2 * ip]     = rmin2[ip].x;
        red[tx * 128 + ty * 8 + 2 * ip + 1] = rmin2[ip].y;
    }
    __syncthreads();
    if (tid < 128) {
        float m = red[tid];
#pragma unroll
        for (int k = 1; k < 16; ++k) m = fminf(m, red[k * 128 + tid]);
        rowpart[((size_t)b * 2 + ph) * NN + gtblk * 128 + tid] = m;
    }
}

__global__ __launch_bounds__(256) void red_k(const float* __restrict__ rowpart,
                                             const float* __restrict__ colpart,
                                             float* __restrict__ acc,
                                             unsigned* __restrict__ bmax,
                                             unsigned* __restrict__ cnt,
                                             float* __restrict__ out) {
    const int b = blockIdx.x, y = blockIdx.y, tid = threadIdx.x;
    __shared__ float a1[4], a2[4];

    if (y < 8) {
        const int p = y * 256 + tid;
        const float* cp = colpart + (size_t)b * 64 * MM + p;
        float m = 3.4e38f;
#pragma unroll 8
        for (int g = 0; g < 64; ++g) m = fminf(m, cp[(size_t)g * MM]);
        float s = m, mx = m;
#pragma unroll
        for (int o = 32; o > 0; o >>= 1) {
            s += __shfl_down(s, o, 64);
            mx = fmaxf(mx, __shfl_down(mx, o, 64));
        }
        const int w = tid >> 6, lane = tid & 63;
        if (lane == 0) { a1[w] = s; a2[w] = mx; }
        __syncthreads();
        if (tid == 0) {
            float cs = a1[0] + a1[1] + a1[2] + a1[3];
            float cm = fmaxf(fmaxf(a2[0], a2[1]), fmaxf(a2[2], a2[3]));
            atomicAdd(acc, cs / (float)(BB * MM));          // loss_1 contribution
            atomicMax(&bmax[b], __float_as_uint(cm));       // per-batch col max
        }
    } else {
        const float* r = rowpart + (size_t)b * 2 * NN;
        float s = 0.0f;
        for (int i = tid; i < NN; i += 256) s += fminf(r[i], r[NN + i]);
#pragma unroll
        for (int o = 32; o > 0; o >>= 1) s += __shfl_down(s, o, 64);
        const int w = tid >> 6, lane = tid & 63;
        if (lane == 0) a1[w] = s;
        __syncthreads();
        if (tid == 0)
            atomicAdd(acc, (a1[0] + a1[1] + a1[2] + a1[3]) / (float)(BB * NN)); // loss_2
    }

    if (tid == 0) {
        __threadfence();
        unsigned old = atomicAdd(cnt, 1u);
        if (old == 71u) {                    // last of 72 blocks
            __threadfence();
            float a = atomicAdd(acc, 0.0f);  // fetch final sum
            float mm = 0.0f;
#pragma unroll
            for (int bb = 0; bb < 8; ++bb)
                mm += __uint_as_float(atomicMax(&bmax[bb], 0u));
            out[0] = a + mm / (float)BB;     // + loss_m
        }
    }
}

extern "C" void kernel_launch(void* const* d_in, const int* in_sizes, int n_in,
                              void* d_out, int out_size, void* d_ws, size_t ws_size,
                              hipStream_t stream) {
    const float* preds = (const float*)d_in[0];
    const float* gts   = (const float*)d_in[1];
    float* out = (float*)d_out;

    // ws (floats): rowpart[2*8*8192] | colpart[8*64*2048] | acc[1] | bmax[8] | cnt[1]
    float* rowpart = (float*)d_ws;
    float* colpart = rowpart + (size_t)2 * BB * NN;
    float* acc     = colpart + (size_t)BB * 64 * MM;
    unsigned* bmax = (unsigned*)(acc + 1);
    unsigned* cnt  = bmax + 8;

    pair_k<<<1024, 256, 0, stream>>>(preds, gts, rowpart, colpart, acc, bmax, cnt);
    red_k<<<dim3(BB, 9), 256, 0, stream>>>(rowpart, colpart, acc, bmax, cnt, out);
}